// Round 2
// baseline (733.316 us; speedup 1.0000x reference)
//
#include <hip/hip_runtime.h>

#define NN 8192
#define NE 262144

typedef short bf16x8 __attribute__((ext_vector_type(8)));
typedef float f32x16 __attribute__((ext_vector_type(16)));

__device__ __forceinline__ unsigned short f2bf(float f) {
  unsigned u = __float_as_uint(f);
  u += 0x7fffu + ((u >> 16) & 1u);
  return (unsigned short)(u >> 16);
}

// ---------------- prep: transpose+convert weights, zero counts ----------------
__global__ void k_prep(const float* __restrict__ W1, const float* __restrict__ W2,
                       unsigned short* __restrict__ W1t, unsigned short* __restrict__ W2t,
                       int* __restrict__ counts) {
  int id = blockIdx.x * blockDim.x + threadIdx.x;
  int stride = gridDim.x * blockDim.x;
  for (int t = id; t < 512 * 256; t += stride) {
    int k = t >> 8, c = t & 255;               // W1[k][c] -> W1t[c][k]
    W1t[c * 512 + k] = f2bf(W1[t]);
  }
  for (int t = id; t < 256 * 128; t += stride) {
    int k = t >> 7, c = t & 127;               // W2[k][c] -> W2t[c][k]
    W2t[c * 256 + k] = f2bf(W2[t]);
  }
  for (int t = id; t < NN; t += stride) counts[t] = 0;
}

// ---------------- CSR build ----------------
__global__ void k_hist(const int* __restrict__ rows, int* __restrict__ counts) {
  int id = blockIdx.x * blockDim.x + threadIdx.x;
  if (id < NE) atomicAdd(&counts[rows[id]], 1);
}

__global__ void k_scan(const int* __restrict__ counts, int* __restrict__ starts,
                       int* __restrict__ cursor) {
  __shared__ int sums[1024];
  int t = threadIdx.x;
  int base = t * 8;
  int local[8];
  int s = 0;
  #pragma unroll
  for (int i = 0; i < 8; ++i) { local[i] = s; s += counts[base + i]; }
  sums[t] = s;
  __syncthreads();
  for (int off = 1; off < 1024; off <<= 1) {
    int v = 0;
    if (t >= off) v = sums[t - off];
    __syncthreads();
    sums[t] += v;
    __syncthreads();
  }
  int pre = sums[t] - s;   // exclusive prefix of this thread's chunk
  #pragma unroll
  for (int i = 0; i < 8; ++i) {
    starts[base + i] = pre + local[i];
    cursor[base + i] = pre + local[i];
  }
  if (t == 1023) starts[NN] = sums[1023];
}

__global__ void k_scatter(const int* __restrict__ rows, int* __restrict__ cursor,
                          int* __restrict__ perm) {
  int id = blockIdx.x * blockDim.x + threadIdx.x;
  if (id < NE) {
    int pos = atomicAdd(&cursor[rows[id]], 1);
    perm[pos] = id;
  }
}

// ---------------- GEMM: C[8192][N] = A[8192][K] * Bt[N][K]^T  (bf16 MFMA) ------
// Tile 128x64, BK=64. 4 waves: (wrow 0..1) x (wcol 0..1); wave tile 64x32.
template <int K, int N, bool AF32>
__global__ __launch_bounds__(256) void k_gemm(const float* __restrict__ Af,
                                              const unsigned short* __restrict__ Ab,
                                              const unsigned short* __restrict__ Bt,
                                              float* __restrict__ C) {
  __shared__ unsigned char As[128 * 64 * 2];   // [128][64] bf16, row=128B, swz ((r&7)<<4)
  __shared__ unsigned char Bs[64 * 64 * 2];    // [64][64]  bf16, row=128B, swz ((r&7)<<4)
  const int tid = threadIdx.x;
  const int r0 = blockIdx.x * 128, c0 = blockIdx.y * 64;
  const int wid = tid >> 6, lane = tid & 63;
  const int wrow = wid >> 1, wcol = wid & 1;
  const int lr = lane & 31, lg = lane >> 5;

  f32x16 acc[2] = {};

  for (int kc = 0; kc < K; kc += 64) {
    __syncthreads();
    // stage A tile (128x64)
    if constexpr (AF32) {
      for (int q = tid; q < 1024; q += 256) {
        int r = q >> 3, s = q & 7;
        const float* gp = Af + (size_t)(r0 + r) * K + kc + s * 8;
        float4 v0 = *(const float4*)gp;
        float4 v1 = *(const float4*)(gp + 4);
        unsigned lo0 = (unsigned)f2bf(v0.x) | ((unsigned)f2bf(v0.y) << 16);
        unsigned hi0 = (unsigned)f2bf(v0.z) | ((unsigned)f2bf(v0.w) << 16);
        unsigned lo1 = (unsigned)f2bf(v1.x) | ((unsigned)f2bf(v1.y) << 16);
        unsigned hi1 = (unsigned)f2bf(v1.z) | ((unsigned)f2bf(v1.w) << 16);
        uint4 u = make_uint4(lo0, hi0, lo1, hi1);
        *(uint4*)(As + r * 128 + ((s * 16) ^ ((r & 7) << 4))) = u;
      }
    } else {
      for (int q = tid; q < 1024; q += 256) {
        int r = q >> 3, s = q & 7;
        float4 v = *(const float4*)(Ab + (size_t)(r0 + r) * K + kc + s * 8);
        *(float4*)(As + r * 128 + ((s * 16) ^ ((r & 7) << 4))) = v;
      }
    }
    // stage B tile (64x64) from Bt[N][K]
    for (int q = tid; q < 512; q += 256) {
      int r = q >> 3, s = q & 7;
      float4 v = *(const float4*)(Bt + (size_t)(c0 + r) * K + kc + s * 8);
      *(float4*)(Bs + r * 128 + ((s * 16) ^ ((r & 7) << 4))) = v;
    }
    __syncthreads();
    #pragma unroll
    for (int ks = 0; ks < 4; ++ks) {
      int brow = wcol * 32 + lr;
      bf16x8 bf = *(const bf16x8*)(Bs + brow * 128 + ((ks * 32 + lg * 16) ^ ((brow & 7) << 4)));
      #pragma unroll
      for (int m = 0; m < 2; ++m) {
        int arow = wrow * 64 + m * 32 + lr;
        bf16x8 af = *(const bf16x8*)(As + arow * 128 + ((ks * 32 + lg * 16) ^ ((arow & 7) << 4)));
        acc[m] = __builtin_amdgcn_mfma_f32_32x32x16_bf16(af, bf, acc[m], 0, 0, 0);
      }
    }
  }
  #pragma unroll
  for (int m = 0; m < 2; ++m) {
    #pragma unroll
    for (int r = 0; r < 16; ++r) {
      int row = r0 + wrow * 64 + m * 32 + (r & 3) + 8 * (r >> 2) + 4 * lg;
      int col = c0 + wcol * 32 + lr;
      C[(size_t)row * N + col] = acc[m][r];
    }
  }
}

// ---------------- SPMM: one wave per row, CSR ----------------
template <int F>
__global__ __launch_bounds__(256) void k_spmm(const int* __restrict__ starts,
                                              const int* __restrict__ perm,
                                              const float* __restrict__ vals,
                                              const int* __restrict__ cols,
                                              const float* __restrict__ S,
                                              float* __restrict__ outF,
                                              unsigned short* __restrict__ outB) {
  constexpr int V = F / 64;   // floats per lane
  int gw = (blockIdx.x * blockDim.x + threadIdx.x) >> 6;
  int lane = threadIdx.x & 63;
  if (gw >= NN) return;
  int s = starts[gw], e = starts[gw + 1];
  float acc[V];
  #pragma unroll
  for (int v = 0; v < V; ++v) acc[v] = 0.f;
  for (int j = s; j < e; ++j) {
    int eid = perm[j];
    float w = vals[eid];
    const float* p = S + (size_t)cols[eid] * F + lane * V;
    if constexpr (V == 4) {
      float4 t = *(const float4*)p;
      acc[0] += w * t.x; acc[1] += w * t.y; acc[2] += w * t.z; acc[3] += w * t.w;
    } else {
      float2 t = *(const float2*)p;
      acc[0] += w * t.x; acc[1] += w * t.y;
    }
  }
  #pragma unroll
  for (int v = 0; v < V; ++v) acc[v] = fmaxf(acc[v], 0.f);
  if constexpr (V == 4) {
    unsigned lo = (unsigned)f2bf(acc[0]) | ((unsigned)f2bf(acc[1]) << 16);
    unsigned hi = (unsigned)f2bf(acc[2]) | ((unsigned)f2bf(acc[3]) << 16);
    *(uint2*)(outB + (size_t)gw * F + lane * 4) = make_uint2(lo, hi);
  } else {
    unsigned lo = (unsigned)f2bf(acc[0]) | ((unsigned)f2bf(acc[1]) << 16);
    *(unsigned int*)(outB + (size_t)gw * F + lane * 2) = lo;
    if (outF) {
      *(float2*)(outF + (size_t)gw * F + lane * 2) = make_float2(acc[0], acc[1]);
    }
  }
}

// ---------------- rec = z z^T, written to two views (write-BW bound) ----------
// Tile 128(i) x 64(j), K=128 full. 4 waves: 2x2, wave tile 64x32.
__global__ __launch_bounds__(256) void k_rec(const unsigned short* __restrict__ zb,
                                             float* __restrict__ out0,
                                             float* __restrict__ out1) {
  __shared__ unsigned char As[128 * 128 * 2];  // [128][128] bf16, row=256B, swz ((r&15)<<4)
  __shared__ unsigned char Bs[64 * 128 * 2];   // [64][128]
  const int tid = threadIdx.x;
  const int i0 = blockIdx.x * 128, j0 = blockIdx.y * 64;

  for (int q = tid; q < 2048; q += 256) {      // A: 128 rows x 16 slots
    int r = q >> 4, s = q & 15;
    float4 v = *(const float4*)(zb + (size_t)(i0 + r) * 128 + s * 8);
    *(float4*)(As + r * 256 + ((s * 16) ^ ((r & 15) << 4))) = v;
  }
  for (int q = tid; q < 1024; q += 256) {      // B: 64 rows x 16 slots
    int r = q >> 4, s = q & 15;
    float4 v = *(const float4*)(zb + (size_t)(j0 + r) * 128 + s * 8);
    *(float4*)(Bs + r * 256 + ((s * 16) ^ ((r & 15) << 4))) = v;
  }
  __syncthreads();

  const int wid = tid >> 6, lane = tid & 63;
  const int wrow = wid >> 1, wcol = wid & 1;
  const int lr = lane & 31, lg = lane >> 5;

  f32x16 acc[2] = {};
  #pragma unroll
  for (int ks = 0; ks < 8; ++ks) {
    int brow = wcol * 32 + lr;
    bf16x8 bf = *(const bf16x8*)(Bs + brow * 256 + ((ks * 32 + lg * 16) ^ ((brow & 15) << 4)));
    #pragma unroll
    for (int m = 0; m < 2; ++m) {
      int arow = wrow * 64 + m * 32 + lr;
      bf16x8 af = *(const bf16x8*)(As + arow * 256 + ((ks * 32 + lg * 16) ^ ((arow & 15) << 4)));
      acc[m] = __builtin_amdgcn_mfma_f32_32x32x16_bf16(af, bf, acc[m], 0, 0, 0);
    }
  }
  #pragma unroll
  for (int m = 0; m < 2; ++m) {
    #pragma unroll
    for (int r = 0; r < 16; ++r) {
      size_t row = i0 + wrow * 64 + m * 32 + (r & 3) + 8 * (r >> 2) + 4 * lg;
      size_t col = j0 + wcol * 32 + lr;
      size_t idx = row * NN + col;
      __builtin_nontemporal_store(acc[m][r], out0 + idx);
      __builtin_nontemporal_store(acc[m][r], out1 + idx);
    }
  }
}

extern "C" void kernel_launch(void* const* d_in, const int* in_sizes, int n_in,
                              void* d_out, int out_size, void* d_ws, size_t ws_size,
                              hipStream_t stream) {
  const float* x     = (const float*)d_in[0];
  const float* W1    = (const float*)d_in[1];
  const float* W2    = (const float*)d_in[2];
  const float* evals = (const float*)d_in[3];
  const int*   erows = (const int*)d_in[4];
  const int*   ecols = (const int*)d_in[5];

  float* out_z   = (float*)d_out;                       // [8192][128]
  float* out_r0  = out_z + (size_t)NN * 128;            // view 0
  float* out_r1  = out_r0 + (size_t)NN * NN;            // view 1

  char* w = (char*)d_ws;
  unsigned short* W1t = (unsigned short*)w;  w += 256 * 512 * 2;
  unsigned short* W2t = (unsigned short*)w;  w += 128 * 256 * 2;
  float*          s1  = (float*)w;           w += (size_t)NN * 256 * 4;
  unsigned short* hb  = (unsigned short*)w;  w += (size_t)NN * 256 * 2;
  float*          s2  = (float*)w;           w += (size_t)NN * 128 * 4;
  unsigned short* zb  = (unsigned short*)w;  w += (size_t)NN * 128 * 2;
  int* counts = (int*)w;                     w += NN * 4;
  int* starts = (int*)w;                     w += (NN + 8) * 4;
  int* cursor = (int*)w;                     w += NN * 4;
  int* perm   = (int*)w;                     w += NE * 4;

  k_prep<<<256, 256, 0, stream>>>(W1, W2, W1t, W2t, counts);
  k_hist<<<NE / 256, 256, 0, stream>>>(erows, counts);
  k_scan<<<1, 1024, 0, stream>>>(counts, starts, cursor);
  k_scatter<<<NE / 256, 256, 0, stream>>>(erows, cursor, perm);

  // layer 1: s1 = x @ W1  (A read as f32, converted in staging)
  k_gemm<512, 256, true><<<dim3(64, 4), 256, 0, stream>>>(x, nullptr, W1t, s1);
  // h = relu(spmm(s1)) -> hb (bf16)
  k_spmm<256><<<NN / 4, 256, 0, stream>>>(starts, perm, evals, ecols, s1, nullptr, hb);
  // layer 2: s2 = h @ W2
  k_gemm<256, 128, false><<<dim3(64, 2), 256, 0, stream>>>(nullptr, hb, W2t, s2);
  // z = relu(spmm(s2)) -> out_z (f32) and zb (bf16)
  k_spmm<128><<<NN / 4, 256, 0, stream>>>(starts, perm, evals, ecols, s2, out_z, zb);
  // rec views
  k_rec<<<dim3(64, 128), 256, 0, stream>>>(zb, out_r0, out_r1);
}